// Round 15
// baseline (93.465 us; speedup 1.0000x reference)
//
#include <hip/hip_runtime.h>
#include <math.h>

#define NB 4
#define NS 2048
#define NF 256
#define NH 8
#define ND 32

constexpr float LN_EPS = 1e-3f;
constexpr float QSCALE = 0.35355339059327373f; // 1/sqrt(H)
constexpr float LOG2E  = 1.4426950408889634f;

typedef __bf16 bf16x8 __attribute__((ext_vector_type(8)));
typedef float f32x4 __attribute__((ext_vector_type(4)));

// ---------------------------------------------------------------------------
// Pre-pass: transpose W[k][n] -> Wt[n][k] bf16 (64 blocks).
// z=0: Wq (scaled QSCALE*LOG2E), z=1: Wk, z=2: Wv, z=3: Wf.
// ---------------------------------------------------------------------------
__global__ __launch_bounds__(256)
void prep_w(const float* __restrict__ Wq, const float* __restrict__ Wk,
            const float* __restrict__ Wv, const float* __restrict__ Wf,
            unsigned short* __restrict__ wt)
{
    __shared__ float tile[64][65];
    const int wid = blockIdx.x;         // 0..63
    const int t = threadIdx.x;
    const int z = wid >> 4;             // 0..3
    const int tl = wid & 15;
    const float* W = (z == 0) ? Wq : (z == 1) ? Wk : (z == 2) ? Wv : Wf;
    const float scale = (z == 0) ? QSCALE * LOG2E : 1.0f;
    const int r0 = (tl >> 2) * 64, c0 = (tl & 3) * 64;
    const int tr = t >> 4, tc4 = (t & 15) * 4;

    #pragma unroll
    for (int p = 0; p < 4; ++p) {
        float4 v = *(const float4*)(W + (size_t)(r0 + tr + p * 16) * NF + c0 + tc4);
        tile[tr + p * 16][tc4 + 0] = v.x;
        tile[tr + p * 16][tc4 + 1] = v.y;
        tile[tr + p * 16][tc4 + 2] = v.z;
        tile[tr + p * 16][tc4 + 3] = v.w;
    }
    __syncthreads();
    #pragma unroll
    for (int p = 0; p < 4; ++p) {
        union { ushort4 u; __bf16 h[4]; } o;
        #pragma unroll
        for (int j = 0; j < 4; ++j)
            o.h[j] = (__bf16)(tile[tc4 + j][tr + p * 16] * scale);
        *(ushort4*)(wt + (size_t)z * 65536 + (size_t)(c0 + tr + p * 16) * NF + r0 + tc4) = o.u;
    }
}

// ---------------------------------------------------------------------------
// Kernel 1: merged QKV projection, bf16 MFMA.  Block = 32 rows x 256 cols x
// ALL 3 z (A-fragments shared across z; x read once).  512 threads / 8 waves,
// wave w owns 32-col slice.  Grid 256 = 1 block/CU, 2 waves/SIMD.
// Q/K stored [B,H,S,D] via LDS-repack -> coalesced ushort8 stores.
// V stored TRANSPOSED [B,H,D,S] via direct ushort4 (s-contiguous).
// ---------------------------------------------------------------------------
__global__ __launch_bounds__(512)
void qkv_mfma(const float* __restrict__ x, const unsigned short* __restrict__ wt,
              unsigned short* __restrict__ qo, unsigned short* __restrict__ ko,
              unsigned short* __restrict__ vo)
{
    const int r0 = blockIdx.x * 32;
    const int t = threadIdx.x;
    const int w = t >> 6, lane = t & 63;
    const int l15 = lane & 15, lhi = lane >> 4;
    const int c0 = w * 32;

    __shared__ unsigned short zs[32][264];

    f32x4 acc[2][2][3] = {};   // [ai][cf][z]

    #pragma unroll 2
    for (int kt = 0; kt < NF; kt += 32) {
        bf16x8 a[2];
        #pragma unroll
        for (int ai = 0; ai < 2; ++ai) {
            const float* xr = x + (size_t)(r0 + ai * 16 + l15) * NF + kt + lhi * 8;
            float4 f0 = *(const float4*)xr;
            float4 f1 = *(const float4*)(xr + 4);
            a[ai][0] = (__bf16)f0.x; a[ai][1] = (__bf16)f0.y;
            a[ai][2] = (__bf16)f0.z; a[ai][3] = (__bf16)f0.w;
            a[ai][4] = (__bf16)f1.x; a[ai][5] = (__bf16)f1.y;
            a[ai][6] = (__bf16)f1.z; a[ai][7] = (__bf16)f1.w;
        }
        #pragma unroll
        for (int z = 0; z < 3; ++z) {
            const unsigned short* W = wt + (size_t)z * 65536;
            #pragma unroll
            for (int cf = 0; cf < 2; ++cf) {
                bf16x8 b = *(const bf16x8*)(W + (size_t)(c0 + cf * 16 + l15) * NF + kt + lhi * 8);
                acc[0][cf][z] = __builtin_amdgcn_mfma_f32_16x16x32_bf16(a[0], b, acc[0][cf][z], 0, 0, 0);
                acc[1][cf][z] = __builtin_amdgcn_mfma_f32_16x16x32_bf16(a[1], b, acc[1][cf][z], 0, 0, 0);
            }
        }
    }

    // ---- epilogue: V^T (z=2) direct, s-contiguous ushort4 ----
    #pragma unroll
    for (int ai = 0; ai < 2; ++ai) {
        #pragma unroll
        for (int cf = 0; cf < 2; ++cf) {
            const int col = c0 + cf * 16 + l15;
            const int h = col >> 5, d = col & 31;
            const int rowbase = r0 + ai * 16 + lhi * 4;
            const int b = rowbase >> 11, s = rowbase & 2047;
            union { ushort4 u; __bf16 h4[4]; } o;
            #pragma unroll
            for (int r = 0; r < 4; ++r) o.h4[r] = (__bf16)acc[ai][cf][2][r];
            *(ushort4*)(vo + ((size_t)(b * NH + h) * ND + d) * NS + s) = o.u;
        }
    }

    // ---- epilogue: Q (z=0), K (z=1) via LDS repack -> coalesced stores ----
    #pragma unroll
    for (int z = 0; z < 2; ++z) {
        __syncthreads();   // previous pass reads done
        #pragma unroll
        for (int ai = 0; ai < 2; ++ai) {
            #pragma unroll
            for (int cf = 0; cf < 2; ++cf) {
                const int col = c0 + cf * 16 + l15;
                #pragma unroll
                for (int r = 0; r < 4; ++r) {
                    __bf16 o = (__bf16)acc[ai][cf][z][r];
                    zs[ai * 16 + lhi * 4 + r][col] = *(unsigned short*)&o;
                }
            }
        }
        __syncthreads();
        unsigned short* out = (z == 0) ? qo : ko;
        #pragma unroll
        for (int p = 0; p < 2; ++p) {
            const int row = (t >> 5) + p * 16;
            const int col8 = (t & 31) * 8;
            const int h = col8 >> 5, d = col8 & 31;
            const int gr = r0 + row;
            const int b = gr >> 11, s = gr & 2047;
            ushort4 u0 = *(ushort4*)&zs[row][col8];
            ushort4 u1 = *(ushort4*)&zs[row][col8 + 4];
            unsigned short* op = out + ((size_t)(b * NH + h) * NS + s) * ND + d;
            *(ushort4*)op = u0;
            *(ushort4*)(op + 4) = u1;
        }
    }
}

// ---------------------------------------------------------------------------
// Kernel 2: flash attention, no-max softmax, P in registers, NO LDS, NO
// BARRIERS.  Block = 4 waves x 32 q-rows = 128 q (proven-best geometry);
// grid (32,16) = 512 blocks = 2/CU.  Per wave-tile: 4 K-frag loads (permuted
// rows) + 4 V^T-frag loads, all direct from global (L2-resident), prefetched
// one tile ahead; 16 MFMA; 32 exp2.  Loads stay in flight across tiles
// (no barrier-forced vmcnt(0) drain).
// ---------------------------------------------------------------------------
__global__ __launch_bounds__(256)
void attn_mfma(const unsigned short* __restrict__ q, const unsigned short* __restrict__ k,
               const unsigned short* __restrict__ v, unsigned short* __restrict__ ctxb)
{
    const int bh = blockIdx.x;            // all s-tiles of one bh share an XCD
    const int s0 = blockIdx.y * 128;
    const int t = threadIdx.x;
    const int w = t >> 6;
    const int lane = t & 63;
    const int l15 = lane & 15;
    const int lhi = lane >> 4;

    const unsigned short* qb  = q + (size_t)bh * NS * ND;
    const unsigned short* kb  = k + (size_t)bh * NS * ND;
    const unsigned short* vg0 = v + (size_t)bh * ND * NS + (size_t)l15 * NS + lhi * 8;       // d=l15
    const unsigned short* vg1 = v + (size_t)bh * ND * NS + (size_t)(16 + l15) * NS + lhi * 8; // d=16+l15

    // permuted K base: key row (l15>>2)*8 + (l15&3); frag offsets 0/128/1024/1152
    const int krow = (l15 >> 2) * 8 + (l15 & 3);
    const unsigned short* kbp = kb + (size_t)krow * ND + lhi * 8;

    bf16x8 qf0 = *(const bf16x8*)(qb + (size_t)(s0 + w * 32 + l15) * ND + lhi * 8);
    bf16x8 qf1 = *(const bf16x8*)(qb + (size_t)(s0 + w * 32 + 16 + l15) * ND + lhi * 8);

    float lp0 = 0.f, lp1 = 0.f;
    f32x4 acc00 = {0.f,0.f,0.f,0.f}, acc01 = {0.f,0.f,0.f,0.f};
    f32x4 acc10 = {0.f,0.f,0.f,0.f}, acc11 = {0.f,0.f,0.f,0.f};

    // ---- prologue: K + V fragments of tile 0 ----
    bf16x8 kf[4], vf[4];
    kf[0] = *(const bf16x8*)(kbp);
    kf[1] = *(const bf16x8*)(kbp + 128);
    kf[2] = *(const bf16x8*)(kbp + 1024);
    kf[3] = *(const bf16x8*)(kbp + 1152);
    vf[0] = *(const bf16x8*)(vg0);        // d=l15,    keys 0..31 slice lhi*8
    vf[1] = *(const bf16x8*)(vg1);        // d=16+l15, keys 0..31
    vf[2] = *(const bf16x8*)(vg0 + 32);   // d=l15,    keys 32..63
    vf[3] = *(const bf16x8*)(vg1 + 32);   // d=16+l15, keys 32..63

    #pragma unroll 2
    for (int tI = 0; tI < 32; ++tI) {
        const int ktn = ((tI + 1) & 31) * 64;   // wraps on last iter: harmless
        // prefetch next tile: K + V fragments -> regs
        bf16x8 kn[4], vn[4];
        kn[0] = *(const bf16x8*)(kbp + (size_t)ktn * ND);
        kn[1] = *(const bf16x8*)(kbp + (size_t)ktn * ND + 128);
        kn[2] = *(const bf16x8*)(kbp + (size_t)ktn * ND + 1024);
        kn[3] = *(const bf16x8*)(kbp + (size_t)ktn * ND + 1152);
        vn[0] = *(const bf16x8*)(vg0 + ktn);
        vn[1] = *(const bf16x8*)(vg1 + ktn);
        vn[2] = *(const bf16x8*)(vg0 + ktn + 32);
        vn[3] = *(const bf16x8*)(vg1 + ktn + 32);

        // QK^T swapped (permuted rows): sc[f][r] =
        //   S[key=(f>>1)*32 + lhi*8 + (f&1)*4 + r][q=l15]   (log2 domain)
        const f32x4 zero = {0.f, 0.f, 0.f, 0.f};
        f32x4 sc0[4], sc1[4];
        __builtin_amdgcn_s_setprio(1);
        #pragma unroll
        for (int f = 0; f < 4; ++f) {
            sc0[f] = __builtin_amdgcn_mfma_f32_16x16x32_bf16(kf[f], qf0, zero, 0, 0, 0);
            sc1[f] = __builtin_amdgcn_mfma_f32_16x16x32_bf16(kf[f], qf1, zero, 0, 0, 0);
        }
        __builtin_amdgcn_s_setprio(0);

        // no-max softmax, P packed straight into PV A-fragments (registers)
        bf16x8 pa00, pa01, pa10, pa11;
        float a0 = 0.f, a1 = 0.f;
        #pragma unroll
        for (int r = 0; r < 4; ++r) {
            float p0 = __builtin_amdgcn_exp2f(sc0[0][r]);
            float p1 = __builtin_amdgcn_exp2f(sc0[1][r]);
            float p2 = __builtin_amdgcn_exp2f(sc0[2][r]);
            float p3 = __builtin_amdgcn_exp2f(sc0[3][r]);
            pa00[r]     = (__bf16)p0;
            pa00[4 + r] = (__bf16)p1;
            pa01[r]     = (__bf16)p2;
            pa01[4 + r] = (__bf16)p3;
            a0 += (p0 + p1) + (p2 + p3);
            float s0_ = __builtin_amdgcn_exp2f(sc1[0][r]);
            float s1_ = __builtin_amdgcn_exp2f(sc1[1][r]);
            float s2_ = __builtin_amdgcn_exp2f(sc1[2][r]);
            float s3_ = __builtin_amdgcn_exp2f(sc1[3][r]);
            pa10[r]     = (__bf16)s0_;
            pa10[4 + r] = (__bf16)s1_;
            pa11[r]     = (__bf16)s2_;
            pa11[4 + r] = (__bf16)s3_;
            a1 += (s0_ + s1_) + (s2_ + s3_);
        }
        lp0 += a0; lp1 += a1;

        // PV: acc[32q x 32d] += P[32q x 64k] * V[64k x 32d]; V from regs
        __builtin_amdgcn_s_setprio(1);
        acc00 = __builtin_amdgcn_mfma_f32_16x16x32_bf16(pa00, vf[0], acc00, 0, 0, 0);
        acc01 = __builtin_amdgcn_mfma_f32_16x16x32_bf16(pa00, vf[1], acc01, 0, 0, 0);
        acc10 = __builtin_amdgcn_mfma_f32_16x16x32_bf16(pa10, vf[0], acc10, 0, 0, 0);
        acc11 = __builtin_amdgcn_mfma_f32_16x16x32_bf16(pa10, vf[1], acc11, 0, 0, 0);
        acc00 = __builtin_amdgcn_mfma_f32_16x16x32_bf16(pa01, vf[2], acc00, 0, 0, 0);
        acc01 = __builtin_amdgcn_mfma_f32_16x16x32_bf16(pa01, vf[3], acc01, 0, 0, 0);
        acc10 = __builtin_amdgcn_mfma_f32_16x16x32_bf16(pa11, vf[2], acc10, 0, 0, 0);
        acc11 = __builtin_amdgcn_mfma_f32_16x16x32_bf16(pa11, vf[3], acc11, 0, 0, 0);
        __builtin_amdgcn_s_setprio(0);

        // rotate prefetched regs (renamed away by unroll-2)
        #pragma unroll
        for (int f = 0; f < 4; ++f) { kf[f] = kn[f]; vf[f] = vn[f]; }
    }

    // final l reductions: sum the 4 lhi partials for each q=l15
    lp0 += __shfl_xor(lp0, 16);
    lp0 += __shfl_xor(lp0, 32);
    lp1 += __shfl_xor(lp1, 16);
    lp1 += __shfl_xor(lp1, 32);

    const int b = bh >> 3, h = bh & 7;
    #pragma unroll
    for (int r = 0; r < 4; ++r) {
        float inv0 = 1.0f / __shfl(lp0, lhi * 4 + r);
        float inv1 = 1.0f / __shfl(lp1, lhi * 4 + r);
        int row0 = s0 + w * 32 + lhi * 4 + r;
        int row1 = row0 + 16;
        unsigned short* op0 = ctxb + ((size_t)b * NS + row0) * NF + h * ND;
        unsigned short* op1 = ctxb + ((size_t)b * NS + row1) * NF + h * ND;
        __bf16 o00 = (__bf16)(acc00[r] * inv0);
        __bf16 o01 = (__bf16)(acc01[r] * inv0);
        __bf16 o10 = (__bf16)(acc10[r] * inv1);
        __bf16 o11 = (__bf16)(acc11[r] * inv1);
        op0[l15]      = *(unsigned short*)&o00;
        op0[16 + l15] = *(unsigned short*)&o01;
        op1[l15]      = *(unsigned short*)&o10;
        op1[16 + l15] = *(unsigned short*)&o11;
    }
}

// ---------------------------------------------------------------------------
// Kernel 3: y = relu(ctx @ Wf + bf); z = x + y; out = LayerNorm(z).
// 512 threads / 8 waves; wave = 32-col slice (2 waves/SIMD at grid 256).
// LN fused via LDS z-tile + wave shuffle reductions (4 rows per wave).
// ---------------------------------------------------------------------------
__global__ __launch_bounds__(512)
void dense_ln(const unsigned short* __restrict__ ctxb, const unsigned short* __restrict__ wft,
              const float* __restrict__ bfp, const float* __restrict__ x,
              float* __restrict__ out)
{
    const int r0 = blockIdx.x * 32;
    const int t = threadIdx.x;
    const int w = t >> 6;
    const int lane = t & 63;
    const int l15 = lane & 15;
    const int lhi = lane >> 4;
    const int c0 = w * 32;

    __shared__ float zs[32][258];

    f32x4 acc[2][2] = {};

    #pragma unroll 2
    for (int kt = 0; kt < NF; kt += 32) {
        bf16x8 a0 = *(const bf16x8*)(ctxb + (size_t)(r0 + l15) * NF + kt + lhi * 8);
        bf16x8 a1 = *(const bf16x8*)(ctxb + (size_t)(r0 + 16 + l15) * NF + kt + lhi * 8);
        #pragma unroll
        for (int cf = 0; cf < 2; ++cf) {
            bf16x8 b = *(const bf16x8*)(wft + (size_t)(c0 + cf * 16 + l15) * NF + kt + lhi * 8);
            acc[0][cf] = __builtin_amdgcn_mfma_f32_16x16x32_bf16(a0, b, acc[0][cf], 0, 0, 0);
            acc[1][cf] = __builtin_amdgcn_mfma_f32_16x16x32_bf16(a1, b, acc[1][cf], 0, 0, 0);
        }
    }

    // stage y = relu(acc + bias) into LDS
    #pragma unroll
    for (int ai = 0; ai < 2; ++ai) {
        #pragma unroll
        for (int cf = 0; cf < 2; ++cf) {
            const int col = c0 + cf * 16 + l15;
            const float bb = bfp[col];
            #pragma unroll
            for (int r = 0; r < 4; ++r) {
                const int row = ai * 16 + lhi * 4 + r;
                zs[row][col] = fmaxf(acc[ai][cf][r] + bb, 0.0f);
            }
        }
    }
    __syncthreads();

    // LN: wave w handles rows w*4 .. w*4+3; residual added here (vectorized)
    #pragma unroll
    for (int i = 0; i < 4; ++i) {
        const int row = w * 4 + i;
        float4 yv = *(const float4*)&zs[row][lane * 4];
        float4 xv = *(const float4*)(x + (size_t)(r0 + row) * NF + lane * 4);
        float z0 = xv.x + yv.x, z1 = xv.y + yv.y;
        float z2 = xv.z + yv.z, z3 = xv.w + yv.w;
        float sum = z0 + z1 + z2 + z3;
        float sq  = z0*z0 + z1*z1 + z2*z2 + z3*z3;
        #pragma unroll
        for (int o = 1; o < 64; o <<= 1) {
            sum += __shfl_xor(sum, o);
            sq  += __shfl_xor(sq, o);
        }
        float mean = sum * (1.0f / NF);
        float var  = sq * (1.0f / NF) - mean * mean;
        float rstd = rsqrtf(var + LN_EPS);
        float4 o4;
        o4.x = (z0 - mean) * rstd;
        o4.y = (z1 - mean) * rstd;
        o4.z = (z2 - mean) * rstd;
        o4.w = (z3 - mean) * rstd;
        *(float4*)(out + (size_t)(r0 + row) * NF + lane * 4) = o4;
    }
}

// ---------------------------------------------------------------------------
extern "C" void kernel_launch(void* const* d_in, const int* in_sizes, int n_in,
                              void* d_out, int out_size, void* d_ws, size_t ws_size,
                              hipStream_t stream)
{
    const float* x  = (const float*)d_in[0];
    const float* Wq = (const float*)d_in[1];
    const float* Wk = (const float*)d_in[2];
    const float* Wv = (const float*)d_in[3];
    const float* Wf = (const float*)d_in[4];
    const float* bf = (const float*)d_in[5];
    float* out = (float*)d_out;

    const size_t per = (size_t)NB * NH * NS * ND;   // 2M elements
    unsigned short* q    = (unsigned short*)d_ws;
    unsigned short* kk   = q + per;
    unsigned short* vv   = kk + per;                // V^T [B,H,D,S]
    unsigned short* wt   = vv + per;                // 4 * 64K bf16
    unsigned short* ctxb = wt + 4 * 65536;          // bf16 [B*S][F], 2M

    prep_w<<<dim3(64), 256, 0, stream>>>(Wq, Wk, Wv, Wf, wt);
    qkv_mfma<<<dim3(256), 512, 0, stream>>>(x, wt, q, kk, vv);
    attn_mfma<<<dim3(NB * NH, NS / 128), 256, 0, stream>>>(q, kk, vv, ctxb);
    dense_ln<<<dim3((NB * NS) / 32), 512, 0, stream>>>(ctxb, wt + 3 * 65536, bf, x, out);
}

// Round 16
// 76.409 us; speedup vs baseline: 1.2232x; 1.2232x over previous
//
#include <hip/hip_runtime.h>
#include <math.h>

#define NB 4
#define NS 2048
#define NF 256
#define NH 8
#define ND 32

constexpr float LN_EPS = 1e-3f;
constexpr float QSCALE = 0.35355339059327373f; // 1/sqrt(H)
constexpr float LOG2E  = 1.4426950408889634f;

typedef __bf16 bf16x8 __attribute__((ext_vector_type(8)));
typedef float f32x4 __attribute__((ext_vector_type(4)));

// ---------------------------------------------------------------------------
// Pre-pass: transpose W[k][n] -> Wt[n][k] bf16 (64 blocks).
// z=0: Wq (scaled QSCALE*LOG2E), z=1: Wk, z=2: Wv, z=3: Wf.
// ---------------------------------------------------------------------------
__global__ __launch_bounds__(256)
void prep_w(const float* __restrict__ Wq, const float* __restrict__ Wk,
            const float* __restrict__ Wv, const float* __restrict__ Wf,
            unsigned short* __restrict__ wt)
{
    __shared__ float tile[64][65];
    const int wid = blockIdx.x;         // 0..63
    const int t = threadIdx.x;
    const int z = wid >> 4;             // 0..3
    const int tl = wid & 15;
    const float* W = (z == 0) ? Wq : (z == 1) ? Wk : (z == 2) ? Wv : Wf;
    const float scale = (z == 0) ? QSCALE * LOG2E : 1.0f;
    const int r0 = (tl >> 2) * 64, c0 = (tl & 3) * 64;
    const int tr = t >> 4, tc4 = (t & 15) * 4;

    #pragma unroll
    for (int p = 0; p < 4; ++p) {
        float4 v = *(const float4*)(W + (size_t)(r0 + tr + p * 16) * NF + c0 + tc4);
        tile[tr + p * 16][tc4 + 0] = v.x;
        tile[tr + p * 16][tc4 + 1] = v.y;
        tile[tr + p * 16][tc4 + 2] = v.z;
        tile[tr + p * 16][tc4 + 3] = v.w;
    }
    __syncthreads();
    #pragma unroll
    for (int p = 0; p < 4; ++p) {
        union { ushort4 u; __bf16 h[4]; } o;
        #pragma unroll
        for (int j = 0; j < 4; ++j)
            o.h[j] = (__bf16)(tile[tc4 + j][tr + p * 16] * scale);
        *(ushort4*)(wt + (size_t)z * 65536 + (size_t)(c0 + tr + p * 16) * NF + r0 + tc4) = o.u;
    }
}

// ---------------------------------------------------------------------------
// Kernel 1: merged QKV projection, bf16 MFMA.  Block = 32 rows x 256 cols x
// ALL 3 z (A-fragments shared across z; x read once).  512 threads / 8 waves,
// wave w owns 32-col slice.  Grid 256 = 1 block/CU, 2 waves/SIMD.
// Q/K stored [B,H,S,D] via LDS-repack -> coalesced ushort8 stores.
// V stored TRANSPOSED [B,H,D,S] via direct ushort4 (s-contiguous).
// ---------------------------------------------------------------------------
__global__ __launch_bounds__(512)
void qkv_mfma(const float* __restrict__ x, const unsigned short* __restrict__ wt,
              unsigned short* __restrict__ qo, unsigned short* __restrict__ ko,
              unsigned short* __restrict__ vo)
{
    const int r0 = blockIdx.x * 32;
    const int t = threadIdx.x;
    const int w = t >> 6, lane = t & 63;
    const int l15 = lane & 15, lhi = lane >> 4;
    const int c0 = w * 32;

    __shared__ unsigned short zs[32][264];

    f32x4 acc[2][2][3] = {};   // [ai][cf][z]

    #pragma unroll 2
    for (int kt = 0; kt < NF; kt += 32) {
        bf16x8 a[2];
        #pragma unroll
        for (int ai = 0; ai < 2; ++ai) {
            const float* xr = x + (size_t)(r0 + ai * 16 + l15) * NF + kt + lhi * 8;
            float4 f0 = *(const float4*)xr;
            float4 f1 = *(const float4*)(xr + 4);
            a[ai][0] = (__bf16)f0.x; a[ai][1] = (__bf16)f0.y;
            a[ai][2] = (__bf16)f0.z; a[ai][3] = (__bf16)f0.w;
            a[ai][4] = (__bf16)f1.x; a[ai][5] = (__bf16)f1.y;
            a[ai][6] = (__bf16)f1.z; a[ai][7] = (__bf16)f1.w;
        }
        #pragma unroll
        for (int z = 0; z < 3; ++z) {
            const unsigned short* W = wt + (size_t)z * 65536;
            #pragma unroll
            for (int cf = 0; cf < 2; ++cf) {
                bf16x8 b = *(const bf16x8*)(W + (size_t)(c0 + cf * 16 + l15) * NF + kt + lhi * 8);
                acc[0][cf][z] = __builtin_amdgcn_mfma_f32_16x16x32_bf16(a[0], b, acc[0][cf][z], 0, 0, 0);
                acc[1][cf][z] = __builtin_amdgcn_mfma_f32_16x16x32_bf16(a[1], b, acc[1][cf][z], 0, 0, 0);
            }
        }
    }

    // ---- epilogue: V^T (z=2) direct, s-contiguous ushort4 ----
    #pragma unroll
    for (int ai = 0; ai < 2; ++ai) {
        #pragma unroll
        for (int cf = 0; cf < 2; ++cf) {
            const int col = c0 + cf * 16 + l15;
            const int h = col >> 5, d = col & 31;
            const int rowbase = r0 + ai * 16 + lhi * 4;
            const int b = rowbase >> 11, s = rowbase & 2047;
            union { ushort4 u; __bf16 h4[4]; } o;
            #pragma unroll
            for (int r = 0; r < 4; ++r) o.h4[r] = (__bf16)acc[ai][cf][2][r];
            *(ushort4*)(vo + ((size_t)(b * NH + h) * ND + d) * NS + s) = o.u;
        }
    }

    // ---- epilogue: Q (z=0), K (z=1) via LDS repack -> coalesced stores ----
    #pragma unroll
    for (int z = 0; z < 2; ++z) {
        __syncthreads();   // previous pass reads done
        #pragma unroll
        for (int ai = 0; ai < 2; ++ai) {
            #pragma unroll
            for (int cf = 0; cf < 2; ++cf) {
                const int col = c0 + cf * 16 + l15;
                #pragma unroll
                for (int r = 0; r < 4; ++r) {
                    __bf16 o = (__bf16)acc[ai][cf][z][r];
                    zs[ai * 16 + lhi * 4 + r][col] = *(unsigned short*)&o;
                }
            }
        }
        __syncthreads();
        unsigned short* out = (z == 0) ? qo : ko;
        #pragma unroll
        for (int p = 0; p < 2; ++p) {
            const int row = (t >> 5) + p * 16;
            const int col8 = (t & 31) * 8;
            const int h = col8 >> 5, d = col8 & 31;
            const int gr = r0 + row;
            const int b = gr >> 11, s = gr & 2047;
            ushort4 u0 = *(ushort4*)&zs[row][col8];
            ushort4 u1 = *(ushort4*)&zs[row][col8 + 4];
            unsigned short* op = out + ((size_t)(b * NH + h) * NS + s) * ND + d;
            *(ushort4*)op = u0;
            *(ushort4*)(op + 4) = u1;
        }
    }
}

// ---------------------------------------------------------------------------
// Kernel 2: flash attention, no-max softmax, P in registers, KVBLK=128.
// R13 structure (proven best: 128q block, LDS V^T dbuf, 1 barrier/tile) with
// the KV tile doubled to 128 keys -> HALF the barriers (16/block), 32 MFMA
// per barrier.  Tile processed as two 64-key sub-steps to cap live registers.
// K fragments permuted (kappa trick) so P packs straight into PV A-frags.
// ---------------------------------------------------------------------------
__global__ __launch_bounds__(256)
void attn_mfma(const unsigned short* __restrict__ q, const unsigned short* __restrict__ k,
               const unsigned short* __restrict__ v, unsigned short* __restrict__ ctxb)
{
    const int bh = blockIdx.x;            // all s-tiles of one bh share an XCD
    const int s0 = blockIdx.y * 128;
    const int t = threadIdx.x;
    const int w = t >> 6;
    const int lane = t & 63;
    const int l15 = lane & 15;
    const int lhi = lane >> 4;
    const int sx  = l15 & 8;              // ushort-unit XOR swizzle for reads
    const int vd  = w * 8 + (lane >> 3);  // V^T staging: this lane's d-row
    const int vk  = (lane & 7) * 8;       // 8-key column group (x2 per tile)
    const int vsx = vd & 8;               // write-side swizzle (same rule)

    __shared__ unsigned short vt[2][32][136];  // V^T dbuf [d][key 0..127], swz

    const unsigned short* qb  = q + (size_t)bh * NS * ND;
    const unsigned short* kb  = k + (size_t)bh * NS * ND;
    const unsigned short* vtg = v + (size_t)bh * ND * NS + (size_t)vd * NS;

    // permuted K base: key row (l15>>2)*8 + (l15&3)
    // frag element offsets within a 128-key tile:
    //   sub0: 0, 128, 1024, 1152   sub1: 2048, 2176, 3072, 3200
    const int krow = (l15 >> 2) * 8 + (l15 & 3);
    const unsigned short* kbp = kb + (size_t)krow * ND + lhi * 8;
    const int kofs[8] = {0, 128, 1024, 1152, 2048, 2176, 3072, 3200};

    bf16x8 qf0 = *(const bf16x8*)(qb + (size_t)(s0 + w * 32 + l15) * ND + lhi * 8);
    bf16x8 qf1 = *(const bf16x8*)(qb + (size_t)(s0 + w * 32 + 16 + l15) * ND + lhi * 8);

    float lp0 = 0.f, lp1 = 0.f;
    f32x4 acc00 = {0.f,0.f,0.f,0.f}, acc01 = {0.f,0.f,0.f,0.f};
    f32x4 acc10 = {0.f,0.f,0.f,0.f}, acc11 = {0.f,0.f,0.f,0.f};

    // ---- prologue: K frags of tile 0 (permuted), V^T tile 0 staged ----
    bf16x8 kf[8];
    #pragma unroll
    for (int f = 0; f < 8; ++f)
        kf[f] = *(const bf16x8*)(kbp + kofs[f]);
    {
        bf16x8 v0 = *(const bf16x8*)(vtg + vk);
        bf16x8 v1 = *(const bf16x8*)(vtg + vk + 64);
        *(bf16x8*)&vt[0][vd][vk ^ vsx] = v0;
        *(bf16x8*)&vt[0][vd][(vk + 64) ^ vsx] = v1;
    }
    __syncthreads();

    int cur = 0;
    #pragma unroll 2
    for (int tI = 0; tI < 16; ++tI) {
        const int ktn = ((tI + 1) & 15) * 128;   // wraps on last iter: harmless
        // prefetch next tile: V^T 2x8 keys -> regs, 8 K fragments -> regs
        bf16x8 vn0 = *(const bf16x8*)(vtg + ktn + vk);
        bf16x8 vn1 = *(const bf16x8*)(vtg + ktn + vk + 64);
        bf16x8 kn[8];
        #pragma unroll
        for (int f = 0; f < 8; ++f)
            kn[f] = *(const bf16x8*)(kbp + (size_t)ktn * ND + kofs[f]);

        const f32x4 zero = {0.f, 0.f, 0.f, 0.f};
        #pragma unroll
        for (int sub = 0; sub < 2; ++sub) {
            // QK^T swapped (permuted rows), 64 keys of this sub-step
            f32x4 sc0[4], sc1[4];
            __builtin_amdgcn_s_setprio(1);
            #pragma unroll
            for (int f = 0; f < 4; ++f) {
                sc0[f] = __builtin_amdgcn_mfma_f32_16x16x32_bf16(kf[sub * 4 + f], qf0, zero, 0, 0, 0);
                sc1[f] = __builtin_amdgcn_mfma_f32_16x16x32_bf16(kf[sub * 4 + f], qf1, zero, 0, 0, 0);
            }
            __builtin_amdgcn_s_setprio(0);

            // no-max softmax, P packed straight into PV A-fragments
            bf16x8 pa00, pa01, pa10, pa11;
            float a0 = 0.f, a1 = 0.f;
            #pragma unroll
            for (int r = 0; r < 4; ++r) {
                float p0 = __builtin_amdgcn_exp2f(sc0[0][r]);
                float p1 = __builtin_amdgcn_exp2f(sc0[1][r]);
                float p2 = __builtin_amdgcn_exp2f(sc0[2][r]);
                float p3 = __builtin_amdgcn_exp2f(sc0[3][r]);
                pa00[r]     = (__bf16)p0;
                pa00[4 + r] = (__bf16)p1;
                pa01[r]     = (__bf16)p2;
                pa01[4 + r] = (__bf16)p3;
                a0 += (p0 + p1) + (p2 + p3);
                float s0_ = __builtin_amdgcn_exp2f(sc1[0][r]);
                float s1_ = __builtin_amdgcn_exp2f(sc1[1][r]);
                float s2_ = __builtin_amdgcn_exp2f(sc1[2][r]);
                float s3_ = __builtin_amdgcn_exp2f(sc1[3][r]);
                pa10[r]     = (__bf16)s0_;
                pa10[4 + r] = (__bf16)s1_;
                pa11[r]     = (__bf16)s2_;
                pa11[4 + r] = (__bf16)s3_;
                a1 += (s0_ + s1_) + (s2_ + s3_);
            }
            lp0 += a0; lp1 += a1;

            // PV: keys sub*64 .. sub*64+63; V from LDS
            const int co0 = (sub * 64 + lhi * 8) ^ sx;
            const int co1 = (sub * 64 + 32 + lhi * 8) ^ sx;
            bf16x8 vfa0 = *(const bf16x8*)&vt[cur][l15][co0];
            bf16x8 vfb0 = *(const bf16x8*)&vt[cur][16 + l15][co0];
            bf16x8 vfa1 = *(const bf16x8*)&vt[cur][l15][co1];
            bf16x8 vfb1 = *(const bf16x8*)&vt[cur][16 + l15][co1];
            __builtin_amdgcn_s_setprio(1);
            acc00 = __builtin_amdgcn_mfma_f32_16x16x32_bf16(pa00, vfa0, acc00, 0, 0, 0);
            acc01 = __builtin_amdgcn_mfma_f32_16x16x32_bf16(pa00, vfb0, acc01, 0, 0, 0);
            acc10 = __builtin_amdgcn_mfma_f32_16x16x32_bf16(pa10, vfa0, acc10, 0, 0, 0);
            acc11 = __builtin_amdgcn_mfma_f32_16x16x32_bf16(pa10, vfb0, acc11, 0, 0, 0);
            acc00 = __builtin_amdgcn_mfma_f32_16x16x32_bf16(pa01, vfa1, acc00, 0, 0, 0);
            acc01 = __builtin_amdgcn_mfma_f32_16x16x32_bf16(pa01, vfb1, acc01, 0, 0, 0);
            acc10 = __builtin_amdgcn_mfma_f32_16x16x32_bf16(pa11, vfa1, acc10, 0, 0, 0);
            acc11 = __builtin_amdgcn_mfma_f32_16x16x32_bf16(pa11, vfb1, acc11, 0, 0, 0);
            __builtin_amdgcn_s_setprio(0);
        }

        // stage prefetched V^T into the other buffer, rotate K regs
        *(bf16x8*)&vt[cur ^ 1][vd][vk ^ vsx] = vn0;
        *(bf16x8*)&vt[cur ^ 1][vd][(vk + 64) ^ vsx] = vn1;
        #pragma unroll
        for (int f = 0; f < 8; ++f) kf[f] = kn[f];
        __syncthreads();
        cur ^= 1;
    }

    // final l reductions: sum the 4 lhi partials for each q=l15
    lp0 += __shfl_xor(lp0, 16);
    lp0 += __shfl_xor(lp0, 32);
    lp1 += __shfl_xor(lp1, 16);
    lp1 += __shfl_xor(lp1, 32);

    const int b = bh >> 3, h = bh & 7;
    #pragma unroll
    for (int r = 0; r < 4; ++r) {
        float inv0 = 1.0f / __shfl(lp0, lhi * 4 + r);
        float inv1 = 1.0f / __shfl(lp1, lhi * 4 + r);
        int row0 = s0 + w * 32 + lhi * 4 + r;
        int row1 = row0 + 16;
        unsigned short* op0 = ctxb + ((size_t)b * NS + row0) * NF + h * ND;
        unsigned short* op1 = ctxb + ((size_t)b * NS + row1) * NF + h * ND;
        __bf16 o00 = (__bf16)(acc00[r] * inv0);
        __bf16 o01 = (__bf16)(acc01[r] * inv0);
        __bf16 o10 = (__bf16)(acc10[r] * inv1);
        __bf16 o11 = (__bf16)(acc11[r] * inv1);
        op0[l15]      = *(unsigned short*)&o00;
        op0[16 + l15] = *(unsigned short*)&o01;
        op1[l15]      = *(unsigned short*)&o10;
        op1[16 + l15] = *(unsigned short*)&o11;
    }
}

// ---------------------------------------------------------------------------
// Kernel 3: y = relu(ctx @ Wf + bf); z = x + y; out = LayerNorm(z).
// 512 threads / 8 waves; wave = 32-col slice (2 waves/SIMD at grid 256).
// LN fused via LDS z-tile + wave shuffle reductions (4 rows per wave).
// ---------------------------------------------------------------------------
__global__ __launch_bounds__(512)
void dense_ln(const unsigned short* __restrict__ ctxb, const unsigned short* __restrict__ wft,
              const float* __restrict__ bfp, const float* __restrict__ x,
              float* __restrict__ out)
{
    const int r0 = blockIdx.x * 32;
    const int t = threadIdx.x;
    const int w = t >> 6;
    const int lane = t & 63;
    const int l15 = lane & 15;
    const int lhi = lane >> 4;
    const int c0 = w * 32;

    __shared__ float zs[32][258];

    f32x4 acc[2][2] = {};

    #pragma unroll 2
    for (int kt = 0; kt < NF; kt += 32) {
        bf16x8 a0 = *(const bf16x8*)(ctxb + (size_t)(r0 + l15) * NF + kt + lhi * 8);
        bf16x8 a1 = *(const bf16x8*)(ctxb + (size_t)(r0 + 16 + l15) * NF + kt + lhi * 8);
        #pragma unroll
        for (int cf = 0; cf < 2; ++cf) {
            bf16x8 b = *(const bf16x8*)(wft + (size_t)(c0 + cf * 16 + l15) * NF + kt + lhi * 8);
            acc[0][cf] = __builtin_amdgcn_mfma_f32_16x16x32_bf16(a0, b, acc[0][cf], 0, 0, 0);
            acc[1][cf] = __builtin_amdgcn_mfma_f32_16x16x32_bf16(a1, b, acc[1][cf], 0, 0, 0);
        }
    }

    // stage y = relu(acc + bias) into LDS
    #pragma unroll
    for (int ai = 0; ai < 2; ++ai) {
        #pragma unroll
        for (int cf = 0; cf < 2; ++cf) {
            const int col = c0 + cf * 16 + l15;
            const float bb = bfp[col];
            #pragma unroll
            for (int r = 0; r < 4; ++r) {
                const int row = ai * 16 + lhi * 4 + r;
                zs[row][col] = fmaxf(acc[ai][cf][r] + bb, 0.0f);
            }
        }
    }
    __syncthreads();

    // LN: wave w handles rows w*4 .. w*4+3; residual added here (vectorized)
    #pragma unroll
    for (int i = 0; i < 4; ++i) {
        const int row = w * 4 + i;
        float4 yv = *(const float4*)&zs[row][lane * 4];
        float4 xv = *(const float4*)(x + (size_t)(r0 + row) * NF + lane * 4);
        float z0 = xv.x + yv.x, z1 = xv.y + yv.y;
        float z2 = xv.z + yv.z, z3 = xv.w + yv.w;
        float sum = z0 + z1 + z2 + z3;
        float sq  = z0*z0 + z1*z1 + z2*z2 + z3*z3;
        #pragma unroll
        for (int o = 1; o < 64; o <<= 1) {
            sum += __shfl_xor(sum, o);
            sq  += __shfl_xor(sq, o);
        }
        float mean = sum * (1.0f / NF);
        float var  = sq * (1.0f / NF) - mean * mean;
        float rstd = rsqrtf(var + LN_EPS);
        float4 o4;
        o4.x = (z0 - mean) * rstd;
        o4.y = (z1 - mean) * rstd;
        o4.z = (z2 - mean) * rstd;
        o4.w = (z3 - mean) * rstd;
        *(float4*)(out + (size_t)(r0 + row) * NF + lane * 4) = o4;
    }
}

// ---------------------------------------------------------------------------
extern "C" void kernel_launch(void* const* d_in, const int* in_sizes, int n_in,
                              void* d_out, int out_size, void* d_ws, size_t ws_size,
                              hipStream_t stream)
{
    const float* x  = (const float*)d_in[0];
    const float* Wq = (const float*)d_in[1];
    const float* Wk = (const float*)d_in[2];
    const float* Wv = (const float*)d_in[3];
    const float* Wf = (const float*)d_in[4];
    const float* bf = (const float*)d_in[5];
    float* out = (float*)d_out;

    const size_t per = (size_t)NB * NH * NS * ND;   // 2M elements
    unsigned short* q    = (unsigned short*)d_ws;
    unsigned short* kk   = q + per;
    unsigned short* vv   = kk + per;                // V^T [B,H,D,S]
    unsigned short* wt   = vv + per;                // 4 * 64K bf16
    unsigned short* ctxb = wt + 4 * 65536;          // bf16 [B*S][F], 2M

    prep_w<<<dim3(64), 256, 0, stream>>>(Wq, Wk, Wv, Wf, wt);
    qkv_mfma<<<dim3(256), 512, 0, stream>>>(x, wt, q, kk, vv);
    attn_mfma<<<dim3(NB * NH, NS / 128), 256, 0, stream>>>(q, kk, vv, ctxb);
    dense_ln<<<dim3((NB * NS) / 32), 512, 0, stream>>>(ctxb, wt + 3 * 65536, bf, x, out);
}

// Round 19
// 76.057 us; speedup vs baseline: 1.2289x; 1.0046x over previous
//
#include <hip/hip_runtime.h>
#include <math.h>

#define NB 4
#define NS 2048
#define NF 256
#define NH 8
#define ND 32

constexpr float LN_EPS = 1e-3f;
constexpr float QSCALE = 0.35355339059327373f; // 1/sqrt(H)
constexpr float LOG2E  = 1.4426950408889634f;

typedef __bf16 bf16x8 __attribute__((ext_vector_type(8)));
typedef float f32x4 __attribute__((ext_vector_type(4)));

// ---------------------------------------------------------------------------
// Pre-pass: transpose W[k][n] -> Wt[n][k] bf16 (64 blocks).
// z=0: Wq (scaled QSCALE*LOG2E), z=1: Wk, z=2: Wv, z=3: Wf.
// ---------------------------------------------------------------------------
__global__ __launch_bounds__(256)
void prep_w(const float* __restrict__ Wq, const float* __restrict__ Wk,
            const float* __restrict__ Wv, const float* __restrict__ Wf,
            unsigned short* __restrict__ wt)
{
    __shared__ float tile[64][65];
    const int wid = blockIdx.x;         // 0..63
    const int t = threadIdx.x;
    const int z = wid >> 4;             // 0..3
    const int tl = wid & 15;
    const float* W = (z == 0) ? Wq : (z == 1) ? Wk : (z == 2) ? Wv : Wf;
    const float scale = (z == 0) ? QSCALE * LOG2E : 1.0f;
    const int r0 = (tl >> 2) * 64, c0 = (tl & 3) * 64;
    const int tr = t >> 4, tc4 = (t & 15) * 4;

    #pragma unroll
    for (int p = 0; p < 4; ++p) {
        float4 v = *(const float4*)(W + (size_t)(r0 + tr + p * 16) * NF + c0 + tc4);
        tile[tr + p * 16][tc4 + 0] = v.x;
        tile[tr + p * 16][tc4 + 1] = v.y;
        tile[tr + p * 16][tc4 + 2] = v.z;
        tile[tr + p * 16][tc4 + 3] = v.w;
    }
    __syncthreads();
    #pragma unroll
    for (int p = 0; p < 4; ++p) {
        union { ushort4 u; __bf16 h[4]; } o;
        #pragma unroll
        for (int j = 0; j < 4; ++j)
            o.h[j] = (__bf16)(tile[tc4 + j][tr + p * 16] * scale);
        *(ushort4*)(wt + (size_t)z * 65536 + (size_t)(c0 + tr + p * 16) * NF + r0 + tc4) = o.u;
    }
}

// ---------------------------------------------------------------------------
// Kernel 1: merged QKV projection, bf16 MFMA.  Block = 32 rows x 256 cols x
// ALL 3 z (A-fragments shared across z; x read once).  512 threads / 8 waves,
// wave w owns 32-col slice.  Grid 256 = 1 block/CU, 2 waves/SIMD.
// Q/K stored [B,H,S,D] via LDS-repack -> coalesced ushort8 stores.
// V stored TRANSPOSED [B,H,D,S] via direct ushort4 (s-contiguous).
// ---------------------------------------------------------------------------
__global__ __launch_bounds__(512)
void qkv_mfma(const float* __restrict__ x, const unsigned short* __restrict__ wt,
              unsigned short* __restrict__ qo, unsigned short* __restrict__ ko,
              unsigned short* __restrict__ vo)
{
    const int r0 = blockIdx.x * 32;
    const int t = threadIdx.x;
    const int w = t >> 6, lane = t & 63;
    const int l15 = lane & 15, lhi = lane >> 4;
    const int c0 = w * 32;

    __shared__ unsigned short zs[32][264];

    f32x4 acc[2][2][3] = {};   // [ai][cf][z]

    #pragma unroll 2
    for (int kt = 0; kt < NF; kt += 32) {
        bf16x8 a[2];
        #pragma unroll
        for (int ai = 0; ai < 2; ++ai) {
            const float* xr = x + (size_t)(r0 + ai * 16 + l15) * NF + kt + lhi * 8;
            float4 f0 = *(const float4*)xr;
            float4 f1 = *(const float4*)(xr + 4);
            a[ai][0] = (__bf16)f0.x; a[ai][1] = (__bf16)f0.y;
            a[ai][2] = (__bf16)f0.z; a[ai][3] = (__bf16)f0.w;
            a[ai][4] = (__bf16)f1.x; a[ai][5] = (__bf16)f1.y;
            a[ai][6] = (__bf16)f1.z; a[ai][7] = (__bf16)f1.w;
        }
        #pragma unroll
        for (int z = 0; z < 3; ++z) {
            const unsigned short* W = wt + (size_t)z * 65536;
            #pragma unroll
            for (int cf = 0; cf < 2; ++cf) {
                bf16x8 b = *(const bf16x8*)(W + (size_t)(c0 + cf * 16 + l15) * NF + kt + lhi * 8);
                acc[0][cf][z] = __builtin_amdgcn_mfma_f32_16x16x32_bf16(a[0], b, acc[0][cf][z], 0, 0, 0);
                acc[1][cf][z] = __builtin_amdgcn_mfma_f32_16x16x32_bf16(a[1], b, acc[1][cf][z], 0, 0, 0);
            }
        }
    }

    // ---- epilogue: V^T (z=2) direct, s-contiguous ushort4 ----
    #pragma unroll
    for (int ai = 0; ai < 2; ++ai) {
        #pragma unroll
        for (int cf = 0; cf < 2; ++cf) {
            const int col = c0 + cf * 16 + l15;
            const int h = col >> 5, d = col & 31;
            const int rowbase = r0 + ai * 16 + lhi * 4;
            const int b = rowbase >> 11, s = rowbase & 2047;
            union { ushort4 u; __bf16 h4[4]; } o;
            #pragma unroll
            for (int r = 0; r < 4; ++r) o.h4[r] = (__bf16)acc[ai][cf][2][r];
            *(ushort4*)(vo + ((size_t)(b * NH + h) * ND + d) * NS + s) = o.u;
        }
    }

    // ---- epilogue: Q (z=0), K (z=1) via LDS repack -> coalesced stores ----
    #pragma unroll
    for (int z = 0; z < 2; ++z) {
        __syncthreads();   // previous pass reads done
        #pragma unroll
        for (int ai = 0; ai < 2; ++ai) {
            #pragma unroll
            for (int cf = 0; cf < 2; ++cf) {
                const int col = c0 + cf * 16 + l15;
                #pragma unroll
                for (int r = 0; r < 4; ++r) {
                    __bf16 o = (__bf16)acc[ai][cf][z][r];
                    zs[ai * 16 + lhi * 4 + r][col] = *(unsigned short*)&o;
                }
            }
        }
        __syncthreads();
        unsigned short* out = (z == 0) ? qo : ko;
        #pragma unroll
        for (int p = 0; p < 2; ++p) {
            const int row = (t >> 5) + p * 16;
            const int col8 = (t & 31) * 8;
            const int h = col8 >> 5, d = col8 & 31;
            const int gr = r0 + row;
            const int b = gr >> 11, s = gr & 2047;
            ushort4 u0 = *(ushort4*)&zs[row][col8];
            ushort4 u1 = *(ushort4*)&zs[row][col8 + 4];
            unsigned short* op = out + ((size_t)(b * NH + h) * NS + s) * ND + d;
            *(ushort4*)op = u0;
            *(ushort4*)(op + 4) = u1;
        }
    }
}

// ---------------------------------------------------------------------------
// Kernel 2: flash attention, no-max softmax, P IN REGISTERS (no split-K).
// Key trick: K fragments loaded with permuted key rows
//   kappa_f(j) = (f>>1)*32 + (j>>2)*8 + (f&1)*4 + (j&3)
// so after swapped QK^T each lane holds exactly the two contiguous 8-key
// A-fragments PV needs.  P never touches LDS.  LDS = V^T dbuf only (9 KB).
// Block = 4 waves x 32 q-rows; 32 tiles of 64 keys; grid (32,16) = 2/CU.
// Epilogue normalizes by 1/l and writes bf16 ctx directly.
// ---------------------------------------------------------------------------
__global__ __launch_bounds__(256)
void attn_mfma(const unsigned short* __restrict__ q, const unsigned short* __restrict__ k,
               const unsigned short* __restrict__ v, unsigned short* __restrict__ ctxb)
{
    const int bh = blockIdx.x;            // all s-tiles of one bh share an XCD
    const int s0 = blockIdx.y * 128;
    const int t = threadIdx.x;
    const int w = t >> 6;
    const int lane = t & 63;
    const int l15 = lane & 15;
    const int lhi = lane >> 4;
    const int sx  = l15 & 8;              // ushort-unit XOR swizzle for reads
    const int vd  = w * 8 + (lane >> 3);  // V^T staging: this lane's d-row
    const int vk  = (lane & 7) * 8;       // and 8-key column group
    const int vsx = vd & 8;               // write-side swizzle (same rule)

    __shared__ unsigned short vt[2][32][72];   // V^T dbuf [d][key], swizzled

    const unsigned short* qb  = q + (size_t)bh * NS * ND;
    const unsigned short* kb  = k + (size_t)bh * NS * ND;
    const unsigned short* vtg = v + (size_t)bh * ND * NS + (size_t)vd * NS;

    const int krow = (l15 >> 2) * 8 + (l15 & 3);
    const unsigned short* kbp = kb + (size_t)krow * ND + lhi * 8;

    bf16x8 qf0 = *(const bf16x8*)(qb + (size_t)(s0 + w * 32 + l15) * ND + lhi * 8);
    bf16x8 qf1 = *(const bf16x8*)(qb + (size_t)(s0 + w * 32 + 16 + l15) * ND + lhi * 8);

    float lp0 = 0.f, lp1 = 0.f;
    f32x4 acc00 = {0.f,0.f,0.f,0.f}, acc01 = {0.f,0.f,0.f,0.f};
    f32x4 acc10 = {0.f,0.f,0.f,0.f}, acc11 = {0.f,0.f,0.f,0.f};

    bf16x8 kf[4];
    kf[0] = *(const bf16x8*)(kbp);
    kf[1] = *(const bf16x8*)(kbp + 128);
    kf[2] = *(const bf16x8*)(kbp + 1024);
    kf[3] = *(const bf16x8*)(kbp + 1152);
    {
        bf16x8 vv = *(const bf16x8*)(vtg + vk);
        *(bf16x8*)&vt[0][vd][vk ^ vsx] = vv;
    }
    __syncthreads();

    int cur = 0;
    #pragma unroll 2
    for (int tI = 0; tI < 32; ++tI) {
        const int ktn = ((tI + 1) & 31) * 64;
        bf16x8 vvn = *(const bf16x8*)(vtg + ktn + vk);
        bf16x8 kn[4];
        kn[0] = *(const bf16x8*)(kbp + (size_t)ktn * ND);
        kn[1] = *(const bf16x8*)(kbp + (size_t)ktn * ND + 128);
        kn[2] = *(const bf16x8*)(kbp + (size_t)ktn * ND + 1024);
        kn[3] = *(const bf16x8*)(kbp + (size_t)ktn * ND + 1152);

        const f32x4 zero = {0.f, 0.f, 0.f, 0.f};
        f32x4 sc0[4], sc1[4];
        __builtin_amdgcn_s_setprio(1);
        #pragma unroll
        for (int f = 0; f < 4; ++f) {
            sc0[f] = __builtin_amdgcn_mfma_f32_16x16x32_bf16(kf[f], qf0, zero, 0, 0, 0);
            sc1[f] = __builtin_amdgcn_mfma_f32_16x16x32_bf16(kf[f], qf1, zero, 0, 0, 0);
        }
        __builtin_amdgcn_s_setprio(0);

        bf16x8 pa00, pa01, pa10, pa11;
        float a0 = 0.f, a1 = 0.f;
        #pragma unroll
        for (int r = 0; r < 4; ++r) {
            float p0 = __builtin_amdgcn_exp2f(sc0[0][r]);
            float p1 = __builtin_amdgcn_exp2f(sc0[1][r]);
            float p2 = __builtin_amdgcn_exp2f(sc0[2][r]);
            float p3 = __builtin_amdgcn_exp2f(sc0[3][r]);
            pa00[r]     = (__bf16)p0;
            pa00[4 + r] = (__bf16)p1;
            pa01[r]     = (__bf16)p2;
            pa01[4 + r] = (__bf16)p3;
            a0 += (p0 + p1) + (p2 + p3);
            float s0_ = __builtin_amdgcn_exp2f(sc1[0][r]);
            float s1_ = __builtin_amdgcn_exp2f(sc1[1][r]);
            float s2_ = __builtin_amdgcn_exp2f(sc1[2][r]);
            float s3_ = __builtin_amdgcn_exp2f(sc1[3][r]);
            pa10[r]     = (__bf16)s0_;
            pa10[4 + r] = (__bf16)s1_;
            pa11[r]     = (__bf16)s2_;
            pa11[4 + r] = (__bf16)s3_;
            a1 += (s0_ + s1_) + (s2_ + s3_);
        }
        lp0 += a0; lp1 += a1;

        const int co0 = (lhi * 8) ^ sx;
        const int co1 = (32 + lhi * 8) ^ sx;
        bf16x8 vfa0 = *(const bf16x8*)&vt[cur][l15][co0];
        bf16x8 vfb0 = *(const bf16x8*)&vt[cur][16 + l15][co0];
        bf16x8 vfa1 = *(const bf16x8*)&vt[cur][l15][co1];
        bf16x8 vfb1 = *(const bf16x8*)&vt[cur][16 + l15][co1];
        __builtin_amdgcn_s_setprio(1);
        acc00 = __builtin_amdgcn_mfma_f32_16x16x32_bf16(pa00, vfa0, acc00, 0, 0, 0);
        acc01 = __builtin_amdgcn_mfma_f32_16x16x32_bf16(pa00, vfb0, acc01, 0, 0, 0);
        acc10 = __builtin_amdgcn_mfma_f32_16x16x32_bf16(pa10, vfa0, acc10, 0, 0, 0);
        acc11 = __builtin_amdgcn_mfma_f32_16x16x32_bf16(pa10, vfb0, acc11, 0, 0, 0);
        acc00 = __builtin_amdgcn_mfma_f32_16x16x32_bf16(pa01, vfa1, acc00, 0, 0, 0);
        acc01 = __builtin_amdgcn_mfma_f32_16x16x32_bf16(pa01, vfb1, acc01, 0, 0, 0);
        acc10 = __builtin_amdgcn_mfma_f32_16x16x32_bf16(pa11, vfa1, acc10, 0, 0, 0);
        acc11 = __builtin_amdgcn_mfma_f32_16x16x32_bf16(pa11, vfb1, acc11, 0, 0, 0);
        __builtin_amdgcn_s_setprio(0);

        *(bf16x8*)&vt[cur ^ 1][vd][vk ^ vsx] = vvn;
        #pragma unroll
        for (int f = 0; f < 4; ++f) kf[f] = kn[f];
        __syncthreads();
        cur ^= 1;
    }

    lp0 += __shfl_xor(lp0, 16);
    lp0 += __shfl_xor(lp0, 32);
    lp1 += __shfl_xor(lp1, 16);
    lp1 += __shfl_xor(lp1, 32);

    const int b = bh >> 3, h = bh & 7;
    #pragma unroll
    for (int r = 0; r < 4; ++r) {
        float inv0 = 1.0f / __shfl(lp0, lhi * 4 + r);
        float inv1 = 1.0f / __shfl(lp1, lhi * 4 + r);
        int row0 = s0 + w * 32 + lhi * 4 + r;
        int row1 = row0 + 16;
        unsigned short* op0 = ctxb + ((size_t)b * NS + row0) * NF + h * ND;
        unsigned short* op1 = ctxb + ((size_t)b * NS + row1) * NF + h * ND;
        __bf16 o00 = (__bf16)(acc00[r] * inv0);
        __bf16 o01 = (__bf16)(acc01[r] * inv0);
        __bf16 o10 = (__bf16)(acc10[r] * inv1);
        __bf16 o11 = (__bf16)(acc11[r] * inv1);
        op0[l15]      = *(unsigned short*)&o00;
        op0[16 + l15] = *(unsigned short*)&o01;
        op1[l15]      = *(unsigned short*)&o10;
        op1[16 + l15] = *(unsigned short*)&o11;
    }
}

// ---------------------------------------------------------------------------
// Kernel 3: y = relu(ctx @ Wf + bf); z = x + y; out = LayerNorm(z).
// 512 threads / 8 waves; wave = 32-col slice (2 waves/SIMD at grid 256).
// LN fused via LDS z-tile + wave shuffle reductions (4 rows per wave).
// ---------------------------------------------------------------------------
__global__ __launch_bounds__(512)
void dense_ln(const unsigned short* __restrict__ ctxb, const unsigned short* __restrict__ wft,
              const float* __restrict__ bfp, const float* __restrict__ x,
              float* __restrict__ out)
{
    const int r0 = blockIdx.x * 32;
    const int t = threadIdx.x;
    const int w = t >> 6;
    const int lane = t & 63;
    const int l15 = lane & 15;
    const int lhi = lane >> 4;
    const int c0 = w * 32;

    __shared__ float zs[32][258];

    f32x4 acc[2][2] = {};

    #pragma unroll 2
    for (int kt = 0; kt < NF; kt += 32) {
        bf16x8 a0 = *(const bf16x8*)(ctxb + (size_t)(r0 + l15) * NF + kt + lhi * 8);
        bf16x8 a1 = *(const bf16x8*)(ctxb + (size_t)(r0 + 16 + l15) * NF + kt + lhi * 8);
        #pragma unroll
        for (int cf = 0; cf < 2; ++cf) {
            bf16x8 b = *(const bf16x8*)(wft + (size_t)(c0 + cf * 16 + l15) * NF + kt + lhi * 8);
            acc[0][cf] = __builtin_amdgcn_mfma_f32_16x16x32_bf16(a0, b, acc[0][cf], 0, 0, 0);
            acc[1][cf] = __builtin_amdgcn_mfma_f32_16x16x32_bf16(a1, b, acc[1][cf], 0, 0, 0);
        }
    }

    // stage y = relu(acc + bias) into LDS
    #pragma unroll
    for (int ai = 0; ai < 2; ++ai) {
        #pragma unroll
        for (int cf = 0; cf < 2; ++cf) {
            const int col = c0 + cf * 16 + l15;
            const float bb = bfp[col];
            #pragma unroll
            for (int r = 0; r < 4; ++r) {
                const int row = ai * 16 + lhi * 4 + r;
                zs[row][col] = fmaxf(acc[ai][cf][r] + bb, 0.0f);
            }
        }
    }
    __syncthreads();

    // LN: wave w handles rows w*4 .. w*4+3; residual added here (vectorized)
    #pragma unroll
    for (int i = 0; i < 4; ++i) {
        const int row = w * 4 + i;
        float4 yv = *(const float4*)&zs[row][lane * 4];
        float4 xv = *(const float4*)(x + (size_t)(r0 + row) * NF + lane * 4);
        float z0 = xv.x + yv.x, z1 = xv.y + yv.y;
        float z2 = xv.z + yv.z, z3 = xv.w + yv.w;
        float sum = z0 + z1 + z2 + z3;
        float sq  = z0*z0 + z1*z1 + z2*z2 + z3*z3;
        #pragma unroll
        for (int o = 1; o < 64; o <<= 1) {
            sum += __shfl_xor(sum, o);
            sq  += __shfl_xor(sq, o);
        }
        float mean = sum * (1.0f / NF);
        float var  = sq * (1.0f / NF) - mean * mean;
        float rstd = rsqrtf(var + LN_EPS);
        float4 o4;
        o4.x = (z0 - mean) * rstd;
        o4.y = (z1 - mean) * rstd;
        o4.z = (z2 - mean) * rstd;
        o4.w = (z3 - mean) * rstd;
        *(float4*)(out + (size_t)(r0 + row) * NF + lane * 4) = o4;
    }
}

// ---------------------------------------------------------------------------
extern "C" void kernel_launch(void* const* d_in, const int* in_sizes, int n_in,
                              void* d_out, int out_size, void* d_ws, size_t ws_size,
                              hipStream_t stream)
{
    const float* x  = (const float*)d_in[0];
    const float* Wq = (const float*)d_in[1];
    const float* Wk = (const float*)d_in[2];
    const float* Wv = (const float*)d_in[3];
    const float* Wf = (const float*)d_in[4];
    const float* bf = (const float*)d_in[5];
    float* out = (float*)d_out;

    const size_t per = (size_t)NB * NH * NS * ND;   // 2M elements
    unsigned short* q    = (unsigned short*)d_ws;
    unsigned short* kk   = q + per;
    unsigned short* vv   = kk + per;                // V^T [B,H,D,S]
    unsigned short* wt   = vv + per;                // 4 * 64K bf16
    unsigned short* ctxb = wt + 4 * 65536;          // bf16 [B*S][F], 2M

    prep_w<<<dim3(64), 256, 0, stream>>>(Wq, Wk, Wv, Wf, wt);
    qkv_mfma<<<dim3(256), 512, 0, stream>>>(x, wt, q, kk, vv);
    attn_mfma<<<dim3(NB * NH, NS / 128), 256, 0, stream>>>(q, kk, vv, ctxb);
    dense_ln<<<dim3((NB * NS) / 32), 512, 0, stream>>>(ctxb, wt + 3 * 65536, bf, x, out);
}